// Round 16
// baseline (12.548 us; speedup 1.0000x reference)
//
#include <hip/hip_runtime.h>

// Problem constants (fixed by reference setup_inputs):
//   B=64, IN=512, OUT=512, K=2, KK=4, T=IN*OUT=262144, TPO=T/OUT=512
constexpr int B    = 64;
constexpr int IN   = 512;
constexpr int OUT  = 512;
constexpr int T    = IN * OUT;
constexpr int TPO  = T / OUT;     // 512 tables per output feature
constexpr int BH   = 32;          // batches per block (one half)
constexpr int ROWB = 80;          // bytes per xs row: 32 bf16 (64B) + 16B pad
// Row starts cycle banks {0,20,8,28,16,4,24,12} over i%8; a tg-group (4
// lanes, same row) reads a contiguous 64B = 16 consecutive banks; 16 random
// tg rows spread evenly over the 8 start positions -> ~2-way worst-case
// aliasing per phase (free, m136). Staging writes: consecutive i, uint4 at
// i*80 + 32h -> 8-lane phases tile banks evenly (conflict-free).

__device__ __forceinline__ unsigned f2bf(float x) {   // round-nearest-even
    unsigned u = __float_as_uint(x);
    return (u + 0x7FFFu + ((u >> 16) & 1u)) >> 16;
}
__device__ __forceinline__ float bf_lo(unsigned u) { return __uint_as_float(u << 16); }
__device__ __forceinline__ float bf_hi(unsigned u) { return __uint_as_float(u & 0xFFFF0000u); }

// R15 economics at 8 waves/SIMD: grid (256 feature-pairs, 2 batch-halves) =
// 512 blocks, ONE resident round (2 blocks/CU; LDS 42 KB, VGPR<=64 via
// launch_bounds(1024,8)). Per CU: same staged bytes, same 256 ds_read_b128,
// same VALU work as R15 -- only mask/lut are read twice chip-wide (L3-hot).
// Wave w: feature o = bx*2 + (w>>3), tables t0 = o*512 + (w&7)*64, 4 steps
// of 16 tables (tg = lane>>2 owns a table, bo = lane&3 owns batches
// 8bo..8bo+7 of this half via ONE ds_read_b128 per operand).
__global__ __launch_bounds__(1024, 8)
void lut_main_kernel(const float* __restrict__ input,   // [B][IN]
                     const int2*  __restrict__ mask2,   // [T]
                     const float4* __restrict__ lut,    // [T][4]
                     const float* __restrict__ bias,    // [OUT]
                     float* __restrict__ out) {         // [B][OUT]
    __shared__ unsigned char xs[IN * ROWB];   // 40 KB bf16 [i][32 batches]
    __shared__ float red[16 * BH];            // 2 KB: [wave][batch-in-half]

    const int tid = threadIdx.x;
    const int H   = blockIdx.y;               // batch half

    // ---- Stage this half's 32 batches as bf16, transposed to [i][b]. ----
    // Thread (i = tid&511, h = tid>>9) covers 16 batches: 16 coalesced
    // loads (issued together), pack to 8 dwords, 2x ds_write_b128.
    {
        const int i = tid & (IN - 1);
        const int h = tid >> 9;
        const float* ip = input + (H * BH + h * 16) * IN + i;
        float a[16];
#pragma unroll
        for (int k = 0; k < 16; ++k) a[k] = ip[k * IN];
        unsigned pk[8];
#pragma unroll
        for (int j = 0; j < 8; ++j)
            pk[j] = f2bf(a[2 * j]) | (f2bf(a[2 * j + 1]) << 16);
        uint4* dst = reinterpret_cast<uint4*>(xs + i * ROWB + h * 32);
        dst[0] = make_uint4(pk[0], pk[1], pk[2], pk[3]);
        dst[1] = make_uint4(pk[4], pk[5], pk[6], pk[7]);
    }
    __syncthreads();

    const int lane = tid & 63;
    const int w    = tid >> 6;          // wave 0..15
    const int o    = blockIdx.x * 2 + (w >> 3);
    const int t0   = o * TPO + (w & 7) * 64;
    const int tg   = lane >> 2;         // table subgroup 0..15
    const int bo   = lane & 3;          // batch octet within the half

    const unsigned char* xb = xs + 16 * bo;
    float acc[8] = {0, 0, 0, 0, 0, 0, 0, 0};
    float accA = 0.f;

#pragma unroll
    for (int s = 0; s < 4; ++s) {
        const int    t = t0 + 16 * s + tg;
        const int2   m = mask2[t];
        const float4 c = lut[t];
        accA += (c.x + c.y + c.z + c.w);
        const float Bc = (-c.x + c.y - c.z + c.w) * 0.25f;
        const float Cc = (-c.x - c.y + c.z + c.w) * 0.25f;
        const float Dd = ( c.x - c.y - c.z + c.w) * 0.25f;
        const uint4 u0 = *reinterpret_cast<const uint4*>(xb + m.x * ROWB);
        const uint4 u1 = *reinterpret_cast<const uint4*>(xb + m.y * ROWB);
        const unsigned p0[4] = {u0.x, u0.y, u0.z, u0.w};
        const unsigned p1[4] = {u1.x, u1.y, u1.z, u1.w};
#pragma unroll
        for (int e = 0; e < 4; ++e) {
            const float x0l = bf_lo(p0[e]), x0h = bf_hi(p0[e]);
            const float x1l = bf_lo(p1[e]), x1h = bf_hi(p1[e]);
            acc[2*e]   = fmaf(Bc, x0l, fmaf(Cc, x1l, fmaf(Dd, x0l * x1l, acc[2*e])));
            acc[2*e+1] = fmaf(Bc, x0h, fmaf(Cc, x1h, fmaf(Dd, x0h * x1h, acc[2*e+1])));
        }
    }

    // Reduce over the 16 tg subgroups (lane bits 2..5); accA rides along.
#pragma unroll
    for (int msk = 4; msk <= 32; msk <<= 1) {
#pragma unroll
        for (int e = 0; e < 8; ++e) acc[e] += __shfl_xor(acc[e], msk);
        accA += __shfl_xor(accA, msk);
    }
    if (tg == 0) {
        const float sA = accA * 0.25f;
#pragma unroll
        for (int e = 0; e < 8; ++e)
            red[w * BH + 8 * bo + e] = acc[e] + sA;
    }
    __syncthreads();

    // Epilogue: 64 threads = 2 features x 32 batches; sum 8 wave partials.
    if (tid < 2 * BH) {
        const int f = tid >> 5;
        const int b = tid & 31;
        float s = 0.f;
#pragma unroll
        for (int q = 0; q < 8; ++q) s += red[(8 * f + q) * BH + b];
        const int oo = blockIdx.x * 2 + f;
        out[(H * BH + b) * OUT + oo] = s + bias[oo];
    }
}

extern "C" void kernel_launch(void* const* d_in, const int* in_sizes, int n_in,
                              void* d_out, int out_size, void* d_ws, size_t ws_size,
                              hipStream_t stream) {
    const float* input = (const float*)d_in[0];
    const int*   mask  = (const int*)d_in[1];
    const float* lut   = (const float*)d_in[2];
    const float* bias  = (const float*)d_in[3];
    float*       out   = (float*)d_out;

    dim3 grid(OUT / 2, 2), block(1024);
    lut_main_kernel<<<grid, block, 0, stream>>>(
        input, (const int2*)mask, (const float4*)lut, bias, out);
}

// Round 17
// 11.569 us; speedup vs baseline: 1.0847x; 1.0847x over previous
//
#include <hip/hip_runtime.h>

// Problem constants (fixed by reference setup_inputs):
//   B=64, IN=512, OUT=512, K=2, KK=4, T=IN*OUT=262144, TPO=T/OUT=512
constexpr int B    = 64;
constexpr int IN   = 512;
constexpr int OUT  = 512;
constexpr int T    = IN * OUT;
constexpr int TPO  = T / OUT;     // 512 tables per output feature
constexpr int ROWB = 144;         // bytes per xs row: 64 bf16 (128B) + 16B pad
// Gather ds_read_b128 at row m, byte 16*bo: a tg-group (8 lanes, same m)
// reads a contiguous 128B row -> all 32 banks exactly once (conflict-free).
// Staging writes: consecutive i at stride 144B -> 8-lane phases tile all
// 32 banks once (conflict-free).

__device__ __forceinline__ unsigned f2bf(float x) {   // round-nearest-even
    unsigned u = __float_as_uint(x);
    return (u + 0x7FFFu + ((u >> 16) & 1u)) >> 16;
}
__device__ __forceinline__ float bf_lo(unsigned u) { return __uint_as_float(u << 16); }
__device__ __forceinline__ float bf_hi(unsigned u) { return __uint_as_float(u & 0xFFFF0000u); }

// R15 config (best: 11.63 us) with one change: inner bilinear evaluated as
// x0*(B + D*x1) + C*x1 (+A via accA) -> 3 fmaf/batch instead of mul+3fmaf.
// grid 256 (1 block/CU), block 1024 = 16 waves (4/SIMD), 2 features/block.
// Wave w: feature o = bx*2+(w>>3), tables t0 = o*512+(w&7)*64, 8 steps of
// 8 tables (tg = lane>>3 owns a table, bo = lane&7 owns batches 8bo..8bo+7
// via ONE ds_read_b128 per operand).
__global__ __launch_bounds__(1024, 4)
void lut_main_kernel(const float* __restrict__ input,   // [B][IN]
                     const int2*  __restrict__ mask2,   // [T]
                     const float4* __restrict__ lut,    // [T][4]
                     const float* __restrict__ bias,    // [OUT]
                     float* __restrict__ out) {         // [B][OUT]
    __shared__ unsigned char xs[IN * ROWB];   // 72 KB bf16 [i][64 batches]
    __shared__ float red[16 * B];             // 4 KB: [wave][batch]

    const int tid = threadIdx.x;

    // ---- Stage input as bf16, transposed: thread (i = tid&511, h = tid>>9)
    // covers batches 32h..32h+31. All 32 coalesced loads issued first (MLP),
    // then pack and 4x ds_write_b128.
    {
        const int i = tid & (IN - 1);
        const int h = tid >> 9;
        const float* ip = input + (h * 32) * IN + i;
        float a[32];
#pragma unroll
        for (int k = 0; k < 32; ++k) a[k] = ip[k * IN];
        unsigned pk[16];
#pragma unroll
        for (int j = 0; j < 16; ++j)
            pk[j] = f2bf(a[2 * j]) | (f2bf(a[2 * j + 1]) << 16);
        uint4* dst = reinterpret_cast<uint4*>(xs + i * ROWB + h * 64);
#pragma unroll
        for (int q = 0; q < 4; ++q)
            dst[q] = make_uint4(pk[4*q], pk[4*q+1], pk[4*q+2], pk[4*q+3]);
    }
    __syncthreads();

    const int lane = tid & 63;
    const int w    = tid >> 6;          // wave 0..15
    const int o    = blockIdx.x * 2 + (w >> 3);
    const int t0   = o * TPO + (w & 7) * 64;
    const int tg   = lane >> 3;         // table subgroup 0..7
    const int bo   = lane & 7;          // batch octet: batches 8bo..8bo+7

    const unsigned char* xb = xs + 16 * bo;
    float acc[8] = {0, 0, 0, 0, 0, 0, 0, 0};
    float accA = 0.f;

#pragma unroll
    for (int s = 0; s < 8; ++s) {
        const int    t = t0 + 8 * s + tg;
        const int2   m = mask2[t];
        const float4 c = lut[t];
        accA += (c.x + c.y + c.z + c.w);
        const float Bc = (-c.x + c.y - c.z + c.w) * 0.25f;
        const float Cc = (-c.x - c.y + c.z + c.w) * 0.25f;
        const float Dd = ( c.x - c.y - c.z + c.w) * 0.25f;
        const uint4 u0 = *reinterpret_cast<const uint4*>(xb + m.x * ROWB);
        const uint4 u1 = *reinterpret_cast<const uint4*>(xb + m.y * ROWB);
        const unsigned p0[4] = {u0.x, u0.y, u0.z, u0.w};
        const unsigned p1[4] = {u1.x, u1.y, u1.z, u1.w};
#pragma unroll
        for (int e = 0; e < 4; ++e) {
            const float x0l = bf_lo(p0[e]), x0h = bf_hi(p0[e]);
            const float x1l = bf_lo(p1[e]), x1h = bf_hi(p1[e]);
            // A + B*x0 + C*x1 + D*x0*x1 = x0*(B + D*x1) + C*x1 (+A via accA)
            acc[2*e]   = fmaf(x0l, fmaf(Dd, x1l, Bc), fmaf(Cc, x1l, acc[2*e]));
            acc[2*e+1] = fmaf(x0h, fmaf(Dd, x1h, Bc), fmaf(Cc, x1h, acc[2*e+1]));
        }
    }

    // Reduce over the 8 tg subgroups (lane bits 3..5); accA rides along.
#pragma unroll
    for (int msk = 8; msk <= 32; msk <<= 1) {
#pragma unroll
        for (int e = 0; e < 8; ++e) acc[e] += __shfl_xor(acc[e], msk);
        accA += __shfl_xor(accA, msk);
    }
    if (tg == 0) {
        const float sA = accA * 0.25f;
#pragma unroll
        for (int e = 0; e < 8; ++e)
            red[w * B + 8 * bo + e] = acc[e] + sA;
    }
    __syncthreads();

    // Cross-wave: 128 threads = 2 features x 64 batches; sum 8 wave partials.
    if (tid < 128) {
        const int f = tid >> 6;
        const int b = tid & 63;
        float s = 0.f;
#pragma unroll
        for (int q = 0; q < 8; ++q) s += red[(8 * f + q) * B + b];
        const int oo = blockIdx.x * 2 + f;
        out[b * OUT + oo] = s + bias[oo];
    }
}

extern "C" void kernel_launch(void* const* d_in, const int* in_sizes, int n_in,
                              void* d_out, int out_size, void* d_ws, size_t ws_size,
                              hipStream_t stream) {
    const float* input = (const float*)d_in[0];
    const int*   mask  = (const int*)d_in[1];
    const float* lut   = (const float*)d_in[2];
    const float* bias  = (const float*)d_in[3];
    float*       out   = (float*)d_out;

    dim3 grid(OUT / 2), block(1024);
    lut_main_kernel<<<grid, block, 0, stream>>>(
        input, (const int2*)mask, (const float4*)lut, bias, out);
}